// Round 9
// baseline (193.293 us; speedup 1.0000x reference)
//
#include <hip/hip_runtime.h>
#include <math.h>

#define NB  8
#define NC  128
#define NN  4096
#define NCQ 16
#define BI  64
#define BJ  64
#define NT  (NN / BJ)
#define WROWS 160   // 16 Q + 16 K + 128 V output channels

typedef __attribute__((ext_vector_type(8))) short short8v;  // 8 x bf16 bits
typedef __attribute__((ext_vector_type(4))) short short4v;
typedef __attribute__((ext_vector_type(4))) float f32x4;

// float -> bf16 (RNE), pure bit manipulation (finite inputs only).
__device__ __forceinline__ short f2bf(float f) {
    unsigned u = __builtin_bit_cast(unsigned, f);
    u += 0x7fffu + ((u >> 16) & 1u);
    return (short)(u >> 16);
}
__device__ __forceinline__ float bf2f(short h) {
    return __builtin_bit_cast(float, ((unsigned)(unsigned short)h) << 16);
}

// ---------------------------------------------------------------------------
// Kernel 0: one-time W -> bf16 hi/lo conversion + bias pack (20480 elements).
// Removes per-block W conversion/staging from the GEMM entirely.
// ---------------------------------------------------------------------------
__global__ __launch_bounds__(256) void wconv(
    const float* __restrict__ wq, const float* __restrict__ bq,
    const float* __restrict__ wk, const float* __restrict__ bk,
    const float* __restrict__ wv, const float* __restrict__ bv,
    short* __restrict__ whg, short* __restrict__ wlg, float* __restrict__ biasg)
{
    const int idx = blockIdx.x * 256 + threadIdx.x;
    if (idx < WROWS * NC) {
        const int row = idx >> 7, k = idx & 127;
        const float v = (row < 16) ? wq[row * NC + k]
                       : (row < 32) ? wk[(row - 16) * NC + k]
                                    : wv[(row - 32) * NC + k];
        const short h = f2bf(v);
        whg[idx] = h;
        wlg[idx] = f2bf(v - bf2f(h));
    }
    if (idx < WROWS)
        biasg[idx] = (idx < 16) ? bq[idx] : (idx < 32) ? bk[idx - 16] : bv[idx - 32];
}

// ---------------------------------------------------------------------------
// Kernel 1 v4: QKV projection GEMM, high-occupancy.
//   out[160][N] = W[160][128] * X[128][N]; 3-plane hi/lo (fp32-accurate).
// Per block (256 thr, 4 waves): 64 columns x all 160 rows. X tile staged
// fp32-coalesced -> transposed+split into LDS xsT[plane][col][k] (35 KB ->
// no occupancy cliff; pad 136 = odd 16B multiple -> b128 reads at the
// 8-lane/16B-slot conflict floor). W fragments = single b128 loads from
// L2-resident pre-converted whg/wlg. 120 MFMAs/wave.
// Fragment convention identical to the HW-verified v3/attn pairing.
// ---------------------------------------------------------------------------
__global__ __launch_bounds__(256) void qkv_gemm(
    const float* __restrict__ x,
    const short* __restrict__ whg, const short* __restrict__ wlg,
    const float* __restrict__ biasg,
    short* __restrict__ Qo, short* __restrict__ Ko, short* __restrict__ Vo)
{
    __shared__ __align__(16) short xsT[2][64][136];   // 34816 B

    const int b  = blockIdx.y;
    const int n0 = blockIdx.x * 64;
    const int t  = threadIdx.x;
    const int w  = t >> 6;
    const int l  = t & 63;
    const int lr = l & 15;
    const int g  = l >> 4;

    const float* xb = x + (size_t)b * NC * NN;

    // stage: coalesced float4 rows -> transposed hi/lo columns
#pragma unroll
    for (int it = 0; it < 8; ++it) {
        const int idx4 = t + 256 * it;
        const int cr = idx4 >> 4;            // k-row 0..127
        const int j4 = (idx4 & 15) * 4;      // local col
        const float4 v = *reinterpret_cast<const float4*>(xb + (size_t)cr * NN + n0 + j4);
        const float vf[4] = {v.x, v.y, v.z, v.w};
#pragma unroll
        for (int p = 0; p < 4; ++p) {
            const short h = f2bf(vf[p]);
            xsT[0][j4 + p][cr] = h;
            xsT[1][j4 + p][cr] = f2bf(vf[p] - bf2f(h));
        }
    }
    __syncthreads();

    const int lc = 16 * w + lr;      // this lane's local column
    f32x4 acc[10];
#pragma unroll
    for (int rt = 0; rt < 10; ++rt) acc[rt] = {0.f, 0.f, 0.f, 0.f};

#pragma unroll
    for (int ks = 0; ks < 4; ++ks) {
        const short8v xh = *reinterpret_cast<const short8v*>(&xsT[0][lc][32 * ks + 8 * g]);
        const short8v xl = *reinterpret_cast<const short8v*>(&xsT[1][lc][32 * ks + 8 * g]);
#pragma unroll
        for (int rt = 0; rt < 10; ++rt) {
            const int wo = (16 * rt + lr) * NC + 32 * ks + 8 * g;
            const short8v ah = *reinterpret_cast<const short8v*>(whg + wo);
            const short8v al = *reinterpret_cast<const short8v*>(wlg + wo);
            acc[rt] = __builtin_amdgcn_mfma_f32_16x16x32_bf16(ah, xh, acc[rt], 0, 0, 0);
            acc[rt] = __builtin_amdgcn_mfma_f32_16x16x32_bf16(ah, xl, acc[rt], 0, 0, 0);
            acc[rt] = __builtin_amdgcn_mfma_f32_16x16x32_bf16(al, xh, acc[rt], 0, 0, 0);
        }
    }

    const int col = n0 + lc;
#pragma unroll
    for (int rt = 0; rt < 10; ++rt) {
#pragma unroll
        for (int r = 0; r < 4; ++r) {
            const int ch = 16 * rt + 4 * g + r;
            const short o = f2bf(acc[rt][r] + biasg[ch]);
            if (rt == 0)
                Qo[((size_t)b * NCQ + ch) * NN + col] = o;
            else if (rt == 1)
                Ko[((size_t)b * NCQ + (ch - 16)) * NN + col] = o;
            else
                Vo[((size_t)b * NC + (ch - 32)) * NN + col] = o;
        }
    }
}

// ---------------------------------------------------------------------------
// Kernel 2 v4: flash attention, skewed pipeline (T15).
// Iter jt: QK(jt) -> exp(jt) -> P_store(jt) -> PV(jt-1) -> stage(jt+1).
// Removes the psT write->read LDS-latency from the critical path and lets
// PV-MFMA overlap the next tile's exp chain. P per-wave double-buffered;
// V triple-buffered (tile m in buf m%3: write(m) in iter m-1, last read in
// iter m+1, overwrite(m+3) in iter m+2 -- one barrier apart each). K stays
// double-buffered (read at iter start only). Accumulation sequence per acc
// is unchanged -> output bit-identical to round 7.
// ---------------------------------------------------------------------------
__global__ __launch_bounds__(256) void attn_mfma(
    const short* __restrict__ Q, const short* __restrict__ K,
    const short* __restrict__ V, const float* __restrict__ x,
    float* __restrict__ out)
{
    __shared__ __align__(16) short ksT[2][BJ * 24];       // 6 KB
    __shared__ __align__(16) short vsT[3][NC * BJ];       // 48 KB
    __shared__ __align__(16) short psT[4][2][16 * BJ];    // 16 KB  (70 KB total)

    const int b  = blockIdx.y;
    const int i0 = blockIdx.x * BI;
    const int t  = threadIdx.x;
    const int w  = t >> 6;
    const int l  = t & 63;
    const int lr = l & 15;
    const int g  = l >> 4;
    const int swz = (lr & 7) << 3;

    const short* Qb = Q + (size_t)b * NCQ * NN;
    const short* Kb = K + (size_t)b * NCQ * NN;
    const short* Vb = V + (size_t)b * NC * NN;

    const int ig = i0 + 16 * w + lr;

    const short8v kzero = {0, 0, 0, 0, 0, 0, 0, 0};
    const f32x4   fzero = {0.f, 0.f, 0.f, 0.f};

    const int kc  = t >> 4;
    const int kj4 = (t & 15) * 4;
    const int vc0 = t >> 3;
    const int vj8 = (t & 7) * 8;

    short4v kreg;
    short8v vreg0, vreg1, vreg2, vreg3;

#define LOAD_TILE(J0)                                                            \
    {                                                                            \
        kreg  = *reinterpret_cast<const short4v*>(Kb + (size_t)kc * NN + (J0) + kj4); \
        vreg0 = *reinterpret_cast<const short8v*>(Vb + (size_t)(vc0      ) * NN + (J0) + vj8); \
        vreg1 = *reinterpret_cast<const short8v*>(Vb + (size_t)(vc0 + 32 ) * NN + (J0) + vj8); \
        vreg2 = *reinterpret_cast<const short8v*>(Vb + (size_t)(vc0 + 64 ) * NN + (J0) + vj8); \
        vreg3 = *reinterpret_cast<const short8v*>(Vb + (size_t)(vc0 + 96 ) * NN + (J0) + vj8); \
    }
#define WRITE_TILE(KB_, VB_)                                                     \
    {                                                                            \
        _Pragma("unroll")                                                        \
        for (int p = 0; p < 4; ++p) ksT[KB_][(kj4 + p) * 24 + kc] = kreg[p];     \
        const int sw0 = vj8 ^ ((vc0 & 7) << 3);                                  \
        *reinterpret_cast<short8v*>(&vsT[VB_][(vc0      ) * BJ + sw0]) = vreg0;  \
        *reinterpret_cast<short8v*>(&vsT[VB_][(vc0 + 32 ) * BJ + sw0]) = vreg1;  \
        *reinterpret_cast<short8v*>(&vsT[VB_][(vc0 + 64 ) * BJ + sw0]) = vreg2;  \
        *reinterpret_cast<short8v*>(&vsT[VB_][(vc0 + 96 ) * BJ + sw0]) = vreg3;  \
    }
#define PV_STEP(PB_, VB_)                                                        \
    {                                                                            \
        __builtin_amdgcn_s_setprio(1);                                           \
        _Pragma("unroll")                                                        \
        for (int ks = 0; ks < 2; ++ks) {                                         \
            const int jb = (32 * ks + 8 * g) ^ swz;                              \
            const short8v pf = *reinterpret_cast<const short8v*>(                \
                    &psT[w][PB_][lr * BJ + jb]);                                 \
            _Pragma("unroll")                                                    \
            for (int cb = 0; cb < 8; ++cb) {                                     \
                const short8v vf = *reinterpret_cast<const short8v*>(            \
                        &vsT[VB_][(16 * cb + lr) * BJ + jb]);                    \
                acc[cb] = __builtin_amdgcn_mfma_f32_16x16x32_bf16(vf, pf, acc[cb], 0, 0, 0); \
            }                                                                    \
        }                                                                        \
        __builtin_amdgcn_s_setprio(0);                                           \
    }

    // Q B-fragment
    short8v qf = kzero;
    if (g < 2) {
        const short* qp = Qb + (size_t)(8 * g) * NN + ig;
#pragma unroll
        for (int e = 0; e < 8; ++e) qf[e] = qp[(size_t)e * NN];
    }

    float l_run = 0.f;
    f32x4 acc[8];
#pragma unroll
    for (int cb = 0; cb < 8; ++cb) acc[cb] = fzero;

    // prologue: tile 0 -> ksT[0], vsT[0]
    LOAD_TILE(0)
    WRITE_TILE(0, 0)
    __syncthreads();

    int vwr = 1;   // vsT buf for WRITE(jt+1) at iter jt   ((jt+1)%3)
    int vpv = 0;   // vsT buf for PV(jt-1)  at iter jt     ((jt-1)%3)

    for (int jt = 0; jt < NT; ++jt) {
        const int kcur = jt & 1;
        if (jt < NT - 1) LOAD_TILE((jt + 1) * BJ)

        // --- QK^T ---
        f32x4 e0, e1, e2, e3;
#define QK_TILE(ET, TT)                                                          \
        {                                                                        \
            short8v kf = kzero;                                                  \
            if (g < 2)                                                           \
                kf = *reinterpret_cast<const short8v*>(                          \
                        &ksT[kcur][(16 * (TT) + lr) * 24 + 8 * g]);              \
            ET = __builtin_amdgcn_mfma_f32_16x16x32_bf16(kf, qf, fzero, 0, 0, 0);\
        }
        QK_TILE(e0, 0) QK_TILE(e1, 1) QK_TILE(e2, 2) QK_TILE(e3, 3)
#undef QK_TILE

        // --- softmax numerator (no max; E bounded ~25) ---
        float sum = 0.f;
#pragma unroll
        for (int r = 0; r < 4; ++r) { e0[r] = __expf(e0[r]); sum += e0[r]; }
#pragma unroll
        for (int r = 0; r < 4; ++r) { e1[r] = __expf(e1[r]); sum += e1[r]; }
#pragma unroll
        for (int r = 0; r < 4; ++r) { e2[r] = __expf(e2[r]); sum += e2[r]; }
#pragma unroll
        for (int r = 0; r < 4; ++r) { e3[r] = __expf(e3[r]); sum += e3[r]; }
        sum += __shfl_xor(sum, 16);
        sum += __shfl_xor(sum, 32);
        l_run += sum;

        // --- P(jt) -> psT[w][jt&1] ---
#define P_STORE(ET, TT)                                                           \
        {                                                                         \
            const int jb = 16 * (TT) + 4 * g;                                     \
            unsigned p01 = (unsigned short)f2bf(ET[0]) |                          \
                           ((unsigned)(unsigned short)f2bf(ET[1]) << 16);         \
            unsigned p23 = (unsigned short)f2bf(ET[2]) |                          \
                           ((unsigned)(unsigned short)f2bf(ET[3]) << 16);         \
            *reinterpret_cast<unsigned*>(&psT[w][kcur][lr * BJ + ( jb      ^ swz)]) = p01; \
            *reinterpret_cast<unsigned*>(&psT[w][kcur][lr * BJ + ((jb + 2) ^ swz)]) = p23; \
        }
        P_STORE(e0, 0) P_STORE(e1, 1) P_STORE(e2, 2) P_STORE(e3, 3)
#undef P_STORE

        // --- PV(jt-1) ---
        if (jt > 0) {
            PV_STEP(kcur ^ 1, vpv)
            vpv = (vpv == 2) ? 0 : vpv + 1;
        }

        // --- stage(jt+1) ---
        if (jt < NT - 1) {
            WRITE_TILE(kcur ^ 1, vwr)
            vwr = (vwr == 2) ? 0 : vwr + 1;
        }
        __syncthreads();
    }

    // tail: PV(NT-1); psT[w][(NT-1)&1], vsT[(NT-1)%3] == vpv
    PV_STEP((NT - 1) & 1, vpv)

#undef LOAD_TILE
#undef WRITE_TILE
#undef PV_STEP

    // --- epilogue ---
    const float inv = 1.f / l_run;
#pragma unroll
    for (int cb = 0; cb < 8; ++cb) {
#pragma unroll
        for (int r = 0; r < 4; ++r) {
            const int c = 16 * cb + 4 * g + r;
            const size_t o = ((size_t)b * NC + c) * NN + ig;
            out[o] = acc[cb][r] * inv + x[o];
        }
    }
}

extern "C" void kernel_launch(void* const* d_in, const int* in_sizes, int n_in,
                              void* d_out, int out_size, void* d_ws, size_t ws_size,
                              hipStream_t stream) {
    const float* x  = (const float*)d_in[0];
    const float* wq = (const float*)d_in[1];
    const float* bq = (const float*)d_in[2];
    const float* wk = (const float*)d_in[3];
    const float* bk = (const float*)d_in[4];
    const float* wv = (const float*)d_in[5];
    const float* bv = (const float*)d_in[6];
    float* out = (float*)d_out;

    short* ws = (short*)d_ws;
    short* Qo  = ws;                                  // [8][16][4096] bf16  1 MB
    short* Ko  = ws + (size_t)NB * NCQ * NN;          // [8][16][4096] bf16  1 MB
    short* Vo  = ws + 2 * (size_t)NB * NCQ * NN;      // [8][128][4096] bf16 8 MB
    short* whg = ws + 10 * (size_t)NB * NCQ * NN;     // [160][128] bf16 hi
    short* wlg = whg + WROWS * NC;                    // [160][128] bf16 lo
    float* biasg = (float*)(wlg + WROWS * NC);        // [160] fp32

    wconv<<<dim3(80), 256, 0, stream>>>(wq, bq, wk, bk, wv, bv, whg, wlg, biasg);
    qkv_gemm<<<dim3(NN / 64, NB), 256, 0, stream>>>(x, whg, wlg, biasg, Qo, Ko, Vo);
    attn_mfma<<<dim3(NN / BI, NB), 256, 0, stream>>>(Qo, Ko, Vo, x, out);
}

// Round 10
// 174.566 us; speedup vs baseline: 1.1073x; 1.1073x over previous
//
#include <hip/hip_runtime.h>
#include <math.h>

#define NB  8
#define NC  128
#define NN  4096
#define NCQ 16
#define BI  64
#define BJ  64
#define NT  (NN / BJ)
#define WROWS 160   // 16 Q + 16 K + 128 V output channels

typedef __attribute__((ext_vector_type(8))) short short8v;  // 8 x bf16 bits
typedef __attribute__((ext_vector_type(4))) short short4v;
typedef __attribute__((ext_vector_type(4))) float f32x4;

// float -> bf16 (RNE), pure bit manipulation (finite inputs only).
__device__ __forceinline__ short f2bf(float f) {
    unsigned u = __builtin_bit_cast(unsigned, f);
    u += 0x7fffu + ((u >> 16) & 1u);
    return (short)(u >> 16);
}
__device__ __forceinline__ float bf2f(short h) {
    return __builtin_bit_cast(float, ((unsigned)(unsigned short)h) << 16);
}

// ---------------------------------------------------------------------------
// Kernel 0: one-time W -> bf16 hi/lo conversion + bias pack. (unchanged)
// ---------------------------------------------------------------------------
__global__ __launch_bounds__(256) void wconv(
    const float* __restrict__ wq, const float* __restrict__ bq,
    const float* __restrict__ wk, const float* __restrict__ bk,
    const float* __restrict__ wv, const float* __restrict__ bv,
    short* __restrict__ whg, short* __restrict__ wlg, float* __restrict__ biasg)
{
    const int idx = blockIdx.x * 256 + threadIdx.x;
    if (idx < WROWS * NC) {
        const int row = idx >> 7, k = idx & 127;
        const float v = (row < 16) ? wq[row * NC + k]
                       : (row < 32) ? wk[(row - 16) * NC + k]
                                    : wv[(row - 32) * NC + k];
        const short h = f2bf(v);
        whg[idx] = h;
        wlg[idx] = f2bf(v - bf2f(h));
    }
    if (idx < WROWS)
        biasg[idx] = (idx < 16) ? bq[idx] : (idx < 32) ? bk[idx - 16] : bv[idx - 32];
}

// ---------------------------------------------------------------------------
// Kernel 1 v4: QKV projection GEMM. UNCHANGED structurally (this round's
// measured change is attn; qkv will finally show its counters now that attn
// drops below it). Only delta: K is stored TRANSPOSED (KoT[b][n][16]) for
// attn's global kf loads.
// ---------------------------------------------------------------------------
__global__ __launch_bounds__(256) void qkv_gemm(
    const float* __restrict__ x,
    const short* __restrict__ whg, const short* __restrict__ wlg,
    const float* __restrict__ biasg,
    short* __restrict__ Qo, short* __restrict__ KoT, short* __restrict__ Vo)
{
    __shared__ __align__(16) short xsT[2][64][136];   // 34816 B

    const int b  = blockIdx.y;
    const int n0 = blockIdx.x * 64;
    const int t  = threadIdx.x;
    const int w  = t >> 6;
    const int l  = t & 63;
    const int lr = l & 15;
    const int g  = l >> 4;

    const float* xb = x + (size_t)b * NC * NN;

    // stage: coalesced float4 rows -> transposed hi/lo columns
#pragma unroll
    for (int it = 0; it < 8; ++it) {
        const int idx4 = t + 256 * it;
        const int cr = idx4 >> 4;            // k-row 0..127
        const int j4 = (idx4 & 15) * 4;      // local col
        const float4 v = *reinterpret_cast<const float4*>(xb + (size_t)cr * NN + n0 + j4);
        const float vf[4] = {v.x, v.y, v.z, v.w};
#pragma unroll
        for (int p = 0; p < 4; ++p) {
            const short h = f2bf(vf[p]);
            xsT[0][j4 + p][cr] = h;
            xsT[1][j4 + p][cr] = f2bf(vf[p] - bf2f(h));
        }
    }
    __syncthreads();

    const int lc = 16 * w + lr;      // this lane's local column
    f32x4 acc[10];
#pragma unroll
    for (int rt = 0; rt < 10; ++rt) acc[rt] = {0.f, 0.f, 0.f, 0.f};

#pragma unroll
    for (int ks = 0; ks < 4; ++ks) {
        const short8v xh = *reinterpret_cast<const short8v*>(&xsT[0][lc][32 * ks + 8 * g]);
        const short8v xl = *reinterpret_cast<const short8v*>(&xsT[1][lc][32 * ks + 8 * g]);
#pragma unroll
        for (int rt = 0; rt < 10; ++rt) {
            const int wo = (16 * rt + lr) * NC + 32 * ks + 8 * g;
            const short8v ah = *reinterpret_cast<const short8v*>(whg + wo);
            const short8v al = *reinterpret_cast<const short8v*>(wlg + wo);
            acc[rt] = __builtin_amdgcn_mfma_f32_16x16x32_bf16(ah, xh, acc[rt], 0, 0, 0);
            acc[rt] = __builtin_amdgcn_mfma_f32_16x16x32_bf16(ah, xl, acc[rt], 0, 0, 0);
            acc[rt] = __builtin_amdgcn_mfma_f32_16x16x32_bf16(al, xh, acc[rt], 0, 0, 0);
        }
    }

    const int col = n0 + lc;
#pragma unroll
    for (int rt = 0; rt < 10; ++rt) {
#pragma unroll
        for (int r = 0; r < 4; ++r) {
            const int ch = 16 * rt + 4 * g + r;
            const short o = f2bf(acc[rt][r] + biasg[ch]);
            if (rt == 0)
                Qo[((size_t)b * NCQ + ch) * NN + col] = o;
            else if (rt == 1)
                KoT[((size_t)b * NN + col) * NCQ + (ch - 16)] = o;   // transposed
            else
                Vo[((size_t)b * NC + (ch - 32)) * NN + col] = o;
        }
    }
}

// ---------------------------------------------------------------------------
// Kernel 2 v5: flash attention, LDS-traffic-minimized (round-9 diagnosis:
// LDS-BW-bound at ~180 KB/CU/iter from 4x V-tile re-reads).
// New decomposition: wave w owns CHANNELS 32w..32w+31 x ALL 64 i.
//   - V and K^T A-fragments load DIRECTLY from global (L2-resident;
//     A-row = lr -> 16 rows x 64B contiguous). NO K/V LDS staging.
//   - QK: wave w computes jj-tile w for all 4 ii-tiles (4 MFMAs, 1 kf).
//   - P shared block-wide via psT[2][64][72] (18 KB, double-buffered);
//     pad 72 -> pf b128 reads land at the 8-lane/16B-slot optimum.
//   - PV(jt-1) overlaps exp(jt); single barrier per iter.
//   - l_run: per-lane partials, shfl-reduced ONCE at end + 1KB cross-wave
//     LDS exchange (removes per-iter shfls).
// LDS/block ~19.5 KB; per-block-iter LDS ~42 KB vs ~102 KB before.
// ---------------------------------------------------------------------------
__global__ __launch_bounds__(256) void attn_mfma(
    const short* __restrict__ Q, const short* __restrict__ KT,
    const short* __restrict__ V, const float* __restrict__ x,
    float* __restrict__ out)
{
    __shared__ __align__(16) short psT[2][64][72];   // 18432 B
    __shared__ float lsumX[4][4][16];                // 1 KB

    const int b  = blockIdx.y;
    const int i0 = blockIdx.x * BI;
    const int t  = threadIdx.x;
    const int w  = t >> 6;
    const int l  = t & 63;
    const int lr = l & 15;
    const int g  = l >> 4;

    const short* Qb  = Q  + (size_t)b * NCQ * NN;
    const short* KTb = KT + (size_t)b * NN * NCQ;
    const short* Vb  = V  + (size_t)b * NC * NN;

    const short8v kzero = {0, 0, 0, 0, 0, 0, 0, 0};
    const f32x4   fzero = {0.f, 0.f, 0.f, 0.f};

    // Q B-fragments for all 4 ii-tiles (col = lr, k-slot (g,e) -> c = 8g+e).
    short8v qf[4] = {kzero, kzero, kzero, kzero};
    if (g < 2) {
#pragma unroll
        for (int it = 0; it < 4; ++it) {
            const short* qp = Qb + (size_t)(8 * g) * NN + i0 + 16 * it + lr;
#pragma unroll
            for (int e = 0; e < 8; ++e) qf[it][e] = qp[(size_t)e * NN];
        }
    }

    // kf prefetch for tile 0: A-row lr -> jj = 16w + lr; c = 8g+e (g<2).
    short8v kfA = kzero;
    if (g < 2)
        kfA = *reinterpret_cast<const short8v*>(KTb + (size_t)(16 * w + lr) * NCQ + 8 * g);

    f32x4 acc[2][4];
#pragma unroll
    for (int ct = 0; ct < 2; ++ct)
#pragma unroll
        for (int it = 0; it < 4; ++it) acc[ct][it] = fzero;
    float lsum[4] = {0.f, 0.f, 0.f, 0.f};

    for (int jt = 0; jt < NT; ++jt) {
        const int cur = jt & 1;

        // prefetch next kf (used at iter jt+1)
        short8v kfB = kzero;
        if (jt + 1 < NT && g < 2)
            kfB = *reinterpret_cast<const short8v*>(
                    KTb + (size_t)((jt + 1) * BJ + 16 * w + lr) * NCQ + 8 * g);

        // V fragments for PV(jt-1): rows 32w+16ct+lr, j = (jt-1)*BJ+32ks+8g+e
        short8v vf00, vf01, vf10, vf11;
        if (jt > 0) {
            const short* vp = Vb + (size_t)(32 * w + lr) * NN + (jt - 1) * BJ + 8 * g;
            vf00 = *reinterpret_cast<const short8v*>(vp);
            vf01 = *reinterpret_cast<const short8v*>(vp + 32);
            vf10 = *reinterpret_cast<const short8v*>(vp + 16 * NN);
            vf11 = *reinterpret_cast<const short8v*>(vp + 16 * NN + 32);
        }

        // --- QK: D[jj = 16w + 4g + r][ii = 16it + lr] ---
        f32x4 e0 = __builtin_amdgcn_mfma_f32_16x16x32_bf16(kfA, qf[0], fzero, 0, 0, 0);
        f32x4 e1 = __builtin_amdgcn_mfma_f32_16x16x32_bf16(kfA, qf[1], fzero, 0, 0, 0);
        f32x4 e2 = __builtin_amdgcn_mfma_f32_16x16x32_bf16(kfA, qf[2], fzero, 0, 0, 0);
        f32x4 e3 = __builtin_amdgcn_mfma_f32_16x16x32_bf16(kfA, qf[3], fzero, 0, 0, 0);

        // --- exp (no max; E bounded ~25) + per-lane l partials ---
#pragma unroll
        for (int r = 0; r < 4; ++r) e0[r] = __expf(e0[r]);
#pragma unroll
        for (int r = 0; r < 4; ++r) e1[r] = __expf(e1[r]);
#pragma unroll
        for (int r = 0; r < 4; ++r) e2[r] = __expf(e2[r]);
#pragma unroll
        for (int r = 0; r < 4; ++r) e3[r] = __expf(e3[r]);
        lsum[0] += (e0[0] + e0[1]) + (e0[2] + e0[3]);
        lsum[1] += (e1[0] + e1[1]) + (e1[2] + e1[3]);
        lsum[2] += (e2[0] + e2[1]) + (e2[2] + e2[3]);
        lsum[3] += (e3[0] + e3[1]) + (e3[2] + e3[3]);

        // --- PV(jt-1): acc[ct][it] += V x P, from psT[prev] ---
        if (jt > 0) {
            const int prev = cur ^ 1;
            __builtin_amdgcn_s_setprio(1);
#pragma unroll
            for (int ks = 0; ks < 2; ++ks) {
#pragma unroll
                for (int it = 0; it < 4; ++it) {
                    const short8v pf = *reinterpret_cast<const short8v*>(
                            &psT[prev][16 * it + lr][32 * ks + 8 * g]);
                    acc[0][it] = __builtin_amdgcn_mfma_f32_16x16x32_bf16(
                            ks ? vf01 : vf00, pf, acc[0][it], 0, 0, 0);
                    acc[1][it] = __builtin_amdgcn_mfma_f32_16x16x32_bf16(
                            ks ? vf11 : vf10, pf, acc[1][it], 0, 0, 0);
                }
            }
            __builtin_amdgcn_s_setprio(0);
        }

        // --- P(jt) -> psT[cur]: row i = 16it+lr, cols j = 16w+4g+{0..3} ---
#define P_STORE(ET, IT)                                                           \
        {                                                                         \
            unsigned p01 = (unsigned short)f2bf(ET[0]) |                          \
                           ((unsigned)(unsigned short)f2bf(ET[1]) << 16);         \
            unsigned p23 = (unsigned short)f2bf(ET[2]) |                          \
                           ((unsigned)(unsigned short)f2bf(ET[3]) << 16);         \
            *reinterpret_cast<unsigned*>(&psT[cur][16 * (IT) + lr][16 * w + 4 * g])     = p01; \
            *reinterpret_cast<unsigned*>(&psT[cur][16 * (IT) + lr][16 * w + 4 * g + 2]) = p23; \
        }
        P_STORE(e0, 0) P_STORE(e1, 1) P_STORE(e2, 2) P_STORE(e3, 3)
#undef P_STORE

        __syncthreads();
        kfA = kfB;
    }

    // --- tail: PV(NT-1) ---
    {
        const int prev = (NT - 1) & 1;
        const short* vp = Vb + (size_t)(32 * w + lr) * NN + (NT - 1) * BJ + 8 * g;
        const short8v vf00 = *reinterpret_cast<const short8v*>(vp);
        const short8v vf01 = *reinterpret_cast<const short8v*>(vp + 32);
        const short8v vf10 = *reinterpret_cast<const short8v*>(vp + 16 * NN);
        const short8v vf11 = *reinterpret_cast<const short8v*>(vp + 16 * NN + 32);
#pragma unroll
        for (int ks = 0; ks < 2; ++ks) {
#pragma unroll
            for (int it = 0; it < 4; ++it) {
                const short8v pf = *reinterpret_cast<const short8v*>(
                        &psT[prev][16 * it + lr][32 * ks + 8 * g]);
                acc[0][it] = __builtin_amdgcn_mfma_f32_16x16x32_bf16(
                        ks ? vf01 : vf00, pf, acc[0][it], 0, 0, 0);
                acc[1][it] = __builtin_amdgcn_mfma_f32_16x16x32_bf16(
                        ks ? vf11 : vf10, pf, acc[1][it], 0, 0, 0);
            }
        }
    }

    // --- l_run: reduce over g (shfl), then over waves (LDS) ---
#pragma unroll
    for (int it = 0; it < 4; ++it) {
        lsum[it] += __shfl_xor(lsum[it], 16);
        lsum[it] += __shfl_xor(lsum[it], 32);
    }
    if (l < 16) {
#pragma unroll
        for (int it = 0; it < 4; ++it) lsumX[w][it][l] = lsum[it];
    }
    __syncthreads();
    float inv[4];
#pragma unroll
    for (int it = 0; it < 4; ++it) {
        const float lr_tot = (lsumX[0][it][lr] + lsumX[1][it][lr]) +
                             (lsumX[2][it][lr] + lsumX[3][it][lr]);
        inv[it] = 1.f / lr_tot;
    }

    // --- epilogue: normalize, residual, store ---
#pragma unroll
    for (int ct = 0; ct < 2; ++ct) {
#pragma unroll
        for (int it = 0; it < 4; ++it) {
#pragma unroll
            for (int r = 0; r < 4; ++r) {
                const int c = 32 * w + 16 * ct + 4 * g + r;
                const size_t o = ((size_t)b * NC + c) * NN + i0 + 16 * it + lr;
                out[o] = acc[ct][it][r] * inv[it] + x[o];
            }
        }
    }
}

extern "C" void kernel_launch(void* const* d_in, const int* in_sizes, int n_in,
                              void* d_out, int out_size, void* d_ws, size_t ws_size,
                              hipStream_t stream) {
    const float* x  = (const float*)d_in[0];
    const float* wq = (const float*)d_in[1];
    const float* bq = (const float*)d_in[2];
    const float* wk = (const float*)d_in[3];
    const float* bk = (const float*)d_in[4];
    const float* wv = (const float*)d_in[5];
    const float* bv = (const float*)d_in[6];
    float* out = (float*)d_out;

    short* ws = (short*)d_ws;
    short* Qo  = ws;                                  // [8][16][4096] bf16  1 MB
    short* KoT = ws + (size_t)NB * NCQ * NN;          // [8][4096][16] bf16  1 MB
    short* Vo  = ws + 2 * (size_t)NB * NCQ * NN;      // [8][128][4096] bf16 8 MB
    short* whg = ws + 10 * (size_t)NB * NCQ * NN;     // [160][128] bf16 hi
    short* wlg = whg + WROWS * NC;                    // [160][128] bf16 lo
    float* biasg = (float*)(wlg + WROWS * NC);        // [160] fp32

    wconv<<<dim3(80), 256, 0, stream>>>(wq, bq, wk, bk, wv, bv, whg, wlg, biasg);
    qkv_gemm<<<dim3(NN / 64, NB), 256, 0, stream>>>(x, whg, wlg, biasg, Qo, KoT, Vo);
    attn_mfma<<<dim3(NN / BI, NB), 256, 0, stream>>>(Qo, KoT, Vo, x, out);
}

// Round 11
// 166.725 us; speedup vs baseline: 1.1594x; 1.0470x over previous
//
#include <hip/hip_runtime.h>
#include <math.h>

#define NB  8
#define NC  128
#define NN  4096
#define NCQ 16
#define BI  64
#define BJ  64
#define NT  (NN / BJ)
#define WROWS 160   // 16 Q + 16 K + 128 V output channels

typedef __attribute__((ext_vector_type(8))) short short8v;  // 8 x bf16 bits
typedef __attribute__((ext_vector_type(4))) short short4v;
typedef __attribute__((ext_vector_type(4))) float f32x4;

// float -> bf16 (RNE), pure bit manipulation (finite inputs only).
__device__ __forceinline__ short f2bf(float f) {
    unsigned u = __builtin_bit_cast(unsigned, f);
    u += 0x7fffu + ((u >> 16) & 1u);
    return (short)(u >> 16);
}
__device__ __forceinline__ float bf2f(short h) {
    return __builtin_bit_cast(float, ((unsigned)(unsigned short)h) << 16);
}

// ---------------------------------------------------------------------------
// Kernel 0: one-time W -> bf16 hi/lo conversion + bias pack. (unchanged)
// ---------------------------------------------------------------------------
__global__ __launch_bounds__(256) void wconv(
    const float* __restrict__ wq, const float* __restrict__ bq,
    const float* __restrict__ wk, const float* __restrict__ bk,
    const float* __restrict__ wv, const float* __restrict__ bv,
    short* __restrict__ whg, short* __restrict__ wlg, float* __restrict__ biasg)
{
    const int idx = blockIdx.x * 256 + threadIdx.x;
    if (idx < WROWS * NC) {
        const int row = idx >> 7, k = idx & 127;
        const float v = (row < 16) ? wq[row * NC + k]
                       : (row < 32) ? wk[(row - 16) * NC + k]
                                    : wv[(row - 32) * NC + k];
        const short h = f2bf(v);
        whg[idx] = h;
        wlg[idx] = f2bf(v - bf2f(h));
    }
    if (idx < WROWS)
        biasg[idx] = (idx < 16) ? bq[idx] : (idx < 32) ? bk[idx - 16] : bv[idx - 32];
}

// ---------------------------------------------------------------------------
// Kernel 1 v4: QKV projection GEMM. BYTE-IDENTICAL to round 10 (no change:
// this round's measured delta is attn-only; with attn dropping below ~85us,
// qkv_gemm will finally surface in the top-5 counter table next round).
// ---------------------------------------------------------------------------
__global__ __launch_bounds__(256) void qkv_gemm(
    const float* __restrict__ x,
    const short* __restrict__ whg, const short* __restrict__ wlg,
    const float* __restrict__ biasg,
    short* __restrict__ Qo, short* __restrict__ KoT, short* __restrict__ Vo)
{
    __shared__ __align__(16) short xsT[2][64][136];   // 34816 B

    const int b  = blockIdx.y;
    const int n0 = blockIdx.x * 64;
    const int t  = threadIdx.x;
    const int w  = t >> 6;
    const int l  = t & 63;
    const int lr = l & 15;
    const int g  = l >> 4;

    const float* xb = x + (size_t)b * NC * NN;

    // stage: coalesced float4 rows -> transposed hi/lo columns
#pragma unroll
    for (int it = 0; it < 8; ++it) {
        const int idx4 = t + 256 * it;
        const int cr = idx4 >> 4;            // k-row 0..127
        const int j4 = (idx4 & 15) * 4;      // local col
        const float4 v = *reinterpret_cast<const float4*>(xb + (size_t)cr * NN + n0 + j4);
        const float vf[4] = {v.x, v.y, v.z, v.w};
#pragma unroll
        for (int p = 0; p < 4; ++p) {
            const short h = f2bf(vf[p]);
            xsT[0][j4 + p][cr] = h;
            xsT[1][j4 + p][cr] = f2bf(vf[p] - bf2f(h));
        }
    }
    __syncthreads();

    const int lc = 16 * w + lr;      // this lane's local column
    f32x4 acc[10];
#pragma unroll
    for (int rt = 0; rt < 10; ++rt) acc[rt] = {0.f, 0.f, 0.f, 0.f};

#pragma unroll
    for (int ks = 0; ks < 4; ++ks) {
        const short8v xh = *reinterpret_cast<const short8v*>(&xsT[0][lc][32 * ks + 8 * g]);
        const short8v xl = *reinterpret_cast<const short8v*>(&xsT[1][lc][32 * ks + 8 * g]);
#pragma unroll
        for (int rt = 0; rt < 10; ++rt) {
            const int wo = (16 * rt + lr) * NC + 32 * ks + 8 * g;
            const short8v ah = *reinterpret_cast<const short8v*>(whg + wo);
            const short8v al = *reinterpret_cast<const short8v*>(wlg + wo);
            acc[rt] = __builtin_amdgcn_mfma_f32_16x16x32_bf16(ah, xh, acc[rt], 0, 0, 0);
            acc[rt] = __builtin_amdgcn_mfma_f32_16x16x32_bf16(ah, xl, acc[rt], 0, 0, 0);
            acc[rt] = __builtin_amdgcn_mfma_f32_16x16x32_bf16(al, xh, acc[rt], 0, 0, 0);
        }
    }

    const int col = n0 + lc;
#pragma unroll
    for (int rt = 0; rt < 10; ++rt) {
#pragma unroll
        for (int r = 0; r < 4; ++r) {
            const int ch = 16 * rt + 4 * g + r;
            const short o = f2bf(acc[rt][r] + biasg[ch]);
            if (rt == 0)
                Qo[((size_t)b * NCQ + ch) * NN + col] = o;
            else if (rt == 1)
                KoT[((size_t)b * NN + col) * NCQ + (ch - 16)] = o;   // transposed
            else
                Vo[((size_t)b * NC + (ch - 32)) * NN + col] = o;
        }
    }
}

// ---------------------------------------------------------------------------
// Kernel 2 v6: flash attention. v5 + two counter-driven fixes:
//  (1) V-fragment DOUBLE-BUFFER: V(jt) issues at iter jt, consumed by PV(jt)
//      at iter jt+1 -> a full iteration (~1000cy) covers L2/HBM latency
//      (v5 gave only ~170cy: QK+exp), which was the measured 40% stall.
//      Loop unrolled x2 with NAMED ping-pong regs (no runtime-indexed reg
//      arrays -> no scratch).
//  (2) P_STORE via v_cvt_pk_bf16_f32 (RNE, 2 f32->1 u32): 8 instrs replace
//      16 manual f2bf (~48 VALU ops) per iter.
// Decomposition unchanged from v5 (wave w: channels 32w..32w+31 x all 64 i;
// K/V direct from global; P block-shared via psT dbuf; PV skewed one tile).
// ---------------------------------------------------------------------------
__global__ __launch_bounds__(256) void attn_mfma(
    const short* __restrict__ Q, const short* __restrict__ KT,
    const short* __restrict__ V, const float* __restrict__ x,
    float* __restrict__ out)
{
    __shared__ __align__(16) short psT[2][64][72];   // 18432 B
    __shared__ float lsumX[4][4][16];                // 1 KB

    const int b  = blockIdx.y;
    const int i0 = blockIdx.x * BI;
    const int t  = threadIdx.x;
    const int w  = t >> 6;
    const int l  = t & 63;
    const int lr = l & 15;
    const int g  = l >> 4;

    const short* Qb  = Q  + (size_t)b * NCQ * NN;
    const short* KTb = KT + (size_t)b * NN * NCQ;
    const short* Vb  = V  + (size_t)b * NC * NN;

    const short8v kzero = {0, 0, 0, 0, 0, 0, 0, 0};
    const f32x4   fzero = {0.f, 0.f, 0.f, 0.f};

    // Q B-fragments for all 4 ii-tiles (col = lr, k-slot (g,e) -> c = 8g+e).
    short8v qf[4] = {kzero, kzero, kzero, kzero};
    if (g < 2) {
#pragma unroll
        for (int it = 0; it < 4; ++it) {
            const short* qp = Qb + (size_t)(8 * g) * NN + i0 + 16 * it + lr;
#pragma unroll
            for (int e = 0; e < 8; ++e) qf[it][e] = qp[(size_t)e * NN];
        }
    }

    // kf for tile 0 (A-row lr -> jj = 16w + lr; c = 8g+e, g<2).
    short8v kfA = kzero, kfB = kzero;
    if (g < 2)
        kfA = *reinterpret_cast<const short8v*>(KTb + (size_t)(16 * w + lr) * NCQ + 8 * g);

    // V-fragment ping-pong buffers (named; rule #20).
    short8v vfE0 = kzero, vfE1 = kzero, vfE2 = kzero, vfE3 = kzero;
    short8v vfO0 = kzero, vfO1 = kzero, vfO2 = kzero, vfO3 = kzero;

    f32x4 acc[2][4];
#pragma unroll
    for (int ct = 0; ct < 2; ++ct)
#pragma unroll
        for (int it = 0; it < 4; ++it) acc[ct][it] = fzero;
    float lsum[4] = {0.f, 0.f, 0.f, 0.f};

    // One iteration. JT: tile index. CUR: JT&1 (compile-time). KUSE holds
    // K(JT); KLOAD <- K(JT+1). VU* hold V(JT-1) (for PV(JT-1)); VL* <- V(JT).
#define ATTN_ITER(JT, CUR, KUSE, KLOAD, VU0, VU1, VU2, VU3, VL0, VL1, VL2, VL3)   \
    {                                                                             \
        if ((JT) + 1 < NT && g < 2)                                               \
            KLOAD = *reinterpret_cast<const short8v*>(                            \
                    KTb + (size_t)(((JT) + 1) * BJ + 16 * w + lr) * NCQ + 8 * g); \
        {                                                                         \
            const short* vp = Vb + (size_t)(32 * w + lr) * NN + (JT) * BJ + 8 * g;\
            VL0 = *reinterpret_cast<const short8v*>(vp);                          \
            VL1 = *reinterpret_cast<const short8v*>(vp + 32);                     \
            VL2 = *reinterpret_cast<const short8v*>(vp + 16 * NN);                \
            VL3 = *reinterpret_cast<const short8v*>(vp + 16 * NN + 32);           \
        }                                                                         \
        f32x4 e0 = __builtin_amdgcn_mfma_f32_16x16x32_bf16(KUSE, qf[0], fzero, 0, 0, 0); \
        f32x4 e1 = __builtin_amdgcn_mfma_f32_16x16x32_bf16(KUSE, qf[1], fzero, 0, 0, 0); \
        f32x4 e2 = __builtin_amdgcn_mfma_f32_16x16x32_bf16(KUSE, qf[2], fzero, 0, 0, 0); \
        f32x4 e3 = __builtin_amdgcn_mfma_f32_16x16x32_bf16(KUSE, qf[3], fzero, 0, 0, 0); \
        _Pragma("unroll")                                                         \
        for (int r = 0; r < 4; ++r) e0[r] = __expf(e0[r]);                        \
        _Pragma("unroll")                                                         \
        for (int r = 0; r < 4; ++r) e1[r] = __expf(e1[r]);                        \
        _Pragma("unroll")                                                         \
        for (int r = 0; r < 4; ++r) e2[r] = __expf(e2[r]);                        \
        _Pragma("unroll")                                                         \
        for (int r = 0; r < 4; ++r) e3[r] = __expf(e3[r]);                        \
        lsum[0] += (e0[0] + e0[1]) + (e0[2] + e0[3]);                             \
        lsum[1] += (e1[0] + e1[1]) + (e1[2] + e1[3]);                             \
        lsum[2] += (e2[0] + e2[1]) + (e2[2] + e2[3]);                             \
        lsum[3] += (e3[0] + e3[1]) + (e3[2] + e3[3]);                             \
        if ((JT) > 0) {                                                           \
            __builtin_amdgcn_s_setprio(1);                                        \
            _Pragma("unroll")                                                     \
            for (int ks = 0; ks < 2; ++ks) {                                      \
                _Pragma("unroll")                                                 \
                for (int it = 0; it < 4; ++it) {                                  \
                    const short8v pf = *reinterpret_cast<const short8v*>(         \
                            &psT[(CUR) ^ 1][16 * it + lr][32 * ks + 8 * g]);      \
                    acc[0][it] = __builtin_amdgcn_mfma_f32_16x16x32_bf16(         \
                            ks ? VU1 : VU0, pf, acc[0][it], 0, 0, 0);             \
                    acc[1][it] = __builtin_amdgcn_mfma_f32_16x16x32_bf16(         \
                            ks ? VU3 : VU2, pf, acc[1][it], 0, 0, 0);             \
                }                                                                 \
            }                                                                     \
            __builtin_amdgcn_s_setprio(0);                                        \
        }                                                                         \
        {                                                                         \
            unsigned p01, p23;                                                    \
            _Pragma("unroll")                                                     \
            for (int it2 = 0; it2 < 4; ++it2) {                                   \
                const f32x4& ee = (it2 == 0) ? e0 : (it2 == 1) ? e1               \
                                 : (it2 == 2) ? e2 : e3;                          \
                asm("v_cvt_pk_bf16_f32 %0, %1, %2"                                \
                    : "=v"(p01) : "v"(ee[0]), "v"(ee[1]));                        \
                asm("v_cvt_pk_bf16_f32 %0, %1, %2"                                \
                    : "=v"(p23) : "v"(ee[2]), "v"(ee[3]));                        \
                *reinterpret_cast<unsigned*>(                                     \
                        &psT[CUR][16 * it2 + lr][16 * w + 4 * g])     = p01;      \
                *reinterpret_cast<unsigned*>(                                     \
                        &psT[CUR][16 * it2 + lr][16 * w + 4 * g + 2]) = p23;      \
            }                                                                     \
        }                                                                         \
        __syncthreads();                                                          \
    }

#pragma unroll 1
    for (int jt2 = 0; jt2 < NT; jt2 += 2) {
        ATTN_ITER(jt2,     0, kfA, kfB, vfO0, vfO1, vfO2, vfO3, vfE0, vfE1, vfE2, vfE3)
        ATTN_ITER(jt2 + 1, 1, kfB, kfA, vfE0, vfE1, vfE2, vfE3, vfO0, vfO1, vfO2, vfO3)
    }
#undef ATTN_ITER

    // --- tail: PV(NT-1); NT-1 odd -> V(NT-1) in vfO*, P in psT[1] ---
    {
        __builtin_amdgcn_s_setprio(1);
#pragma unroll
        for (int ks = 0; ks < 2; ++ks) {
#pragma unroll
            for (int it = 0; it < 4; ++it) {
                const short8v pf = *reinterpret_cast<const short8v*>(
                        &psT[1][16 * it + lr][32 * ks + 8 * g]);
                acc[0][it] = __builtin_amdgcn_mfma_f32_16x16x32_bf16(
                        ks ? vfO1 : vfO0, pf, acc[0][it], 0, 0, 0);
                acc[1][it] = __builtin_amdgcn_mfma_f32_16x16x32_bf16(
                        ks ? vfO3 : vfO2, pf, acc[1][it], 0, 0, 0);
            }
        }
        __builtin_amdgcn_s_setprio(0);
    }

    // --- l_run: reduce over g (shfl), then over waves (LDS) ---
#pragma unroll
    for (int it = 0; it < 4; ++it) {
        lsum[it] += __shfl_xor(lsum[it], 16);
        lsum[it] += __shfl_xor(lsum[it], 32);
    }
    if (l < 16) {
#pragma unroll
        for (int it = 0; it < 4; ++it) lsumX[w][it][l] = lsum[it];
    }
    __syncthreads();
    float inv[4];
#pragma unroll
    for (int it = 0; it < 4; ++it) {
        const float lr_tot = (lsumX[0][it][lr] + lsumX[1][it][lr]) +
                             (lsumX[2][it][lr] + lsumX[3][it][lr]);
        inv[it] = 1.f / lr_tot;
    }

    // --- epilogue: normalize, residual, store ---
#pragma unroll
    for (int ct = 0; ct < 2; ++ct) {
#pragma unroll
        for (int it = 0; it < 4; ++it) {
#pragma unroll
            for (int r = 0; r < 4; ++r) {
                const int c = 32 * w + 16 * ct + 4 * g + r;
                const size_t o = ((size_t)b * NC + c) * NN + i0 + 16 * it + lr;
                out[o] = acc[ct][it][r] * inv[it] + x[o];
            }
        }
    }
}

extern "C" void kernel_launch(void* const* d_in, const int* in_sizes, int n_in,
                              void* d_out, int out_size, void* d_ws, size_t ws_size,
                              hipStream_t stream) {
    const float* x  = (const float*)d_in[0];
    const float* wq = (const float*)d_in[1];
    const float* bq = (const float*)d_in[2];
    const float* wk = (const float*)d_in[3];
    const float* bk = (const float*)d_in[4];
    const float* wv = (const float*)d_in[5];
    const float* bv = (const float*)d_in[6];
    float* out = (float*)d_out;

    short* ws = (short*)d_ws;
    short* Qo  = ws;                                  // [8][16][4096] bf16  1 MB
    short* KoT = ws + (size_t)NB * NCQ * NN;          // [8][4096][16] bf16  1 MB
    short* Vo  = ws + 2 * (size_t)NB * NCQ * NN;      // [8][128][4096] bf16 8 MB
    short* whg = ws + 10 * (size_t)NB * NCQ * NN;     // [160][128] bf16 hi
    short* wlg = whg + WROWS * NC;                    // [160][128] bf16 lo
    float* biasg = (float*)(wlg + WROWS * NC);        // [160] fp32

    wconv<<<dim3(80), 256, 0, stream>>>(wq, bq, wk, bk, wv, bv, whg, wlg, biasg);
    qkv_gemm<<<dim3(NN / 64, NB), 256, 0, stream>>>(x, whg, wlg, biasg, Qo, KoT, Vo);
    attn_mfma<<<dim3(NN / BI, NB), 256, 0, stream>>>(Qo, KoT, Vo, x, out);
}